// Round 4
// baseline (657.300 us; speedup 1.0000x reference)
//
#include <hip/hip_runtime.h>

typedef short bhalf8 __attribute__((ext_vector_type(8)));
typedef float floatx4 __attribute__((ext_vector_type(4)));
typedef unsigned short ushortx8 __attribute__((ext_vector_type(8)));

__device__ __forceinline__ unsigned short f2bf(float f){
  union { float f; unsigned int u; } v; v.f = f;
  unsigned int u = v.u;
  u += 0x7fffu + ((u >> 16) & 1u);
  return (unsigned short)(u >> 16);
}
__device__ __forceinline__ float bf2f(unsigned short u){
  union { unsigned int u; float f; } v; v.u = ((unsigned)u) << 16; return v.f;
}
__device__ __forceinline__ unsigned pack2(float a, float b){
  return (unsigned)f2bf(a) | ((unsigned)f2bf(b) << 16);
}

__device__ __forceinline__ void async16(const unsigned short* g, unsigned short* l){
  __builtin_amdgcn_global_load_lds(
      (const __attribute__((address_space(1))) void*)g,
      (__attribute__((address_space(3))) void*)l,
      16, 0, 0);
}

// ---------------------------------------------------------------------------
// MFMA GEMM: C[M,N] = A[M,K]*B[K,N]; A bf16 [M,K], B transposed bf16 BT[N,K].
// Tile 128x128, BK=64 (32 KB LDS), 4 waves 2x2, 4x4 mfma_f32_16x16x32_bf16 each.
// Staging: global_load_lds w=16, XOR swizzle slot=(row*8 + (c ^ (row&7))).
// R4: (a) EPI1/EPI3 use SWAPPED mfma operands -> thread's 4 acc regs are 4
//     consecutive n -> packed float4/uint2 C-stores + float4 bias (was 64
//     scalar stores). (b) register diet: 1 staging ptr per matrix
//     (slots differ by 32*i*K since the XOR swizzle term is slot-invariant),
//     frag offsets collapse to base + mi*1024, ks via ^32 (byte ^ of cvt^4).
// EPI 0: fp32 C;  1: fp32 C+bias (swapped);  2: bf16 transposed;
// EPI 3: bf16 C+bias (swapped)
// ---------------------------------------------------------------------------
template<int EPI>
__global__ __launch_bounds__(256) void gemm_k(
    const unsigned short* __restrict__ Ab, const unsigned short* __restrict__ BT,
    const float* __restrict__ bias, float* __restrict__ Cf,
    unsigned short* __restrict__ Cb, int K, int ldc)
{
  __shared__ __align__(16) unsigned short As[128*64];
  __shared__ __align__(16) unsigned short Bs[128*64];
  const int tid = threadIdx.x;
  const int n0 = blockIdx.x * 128;
  const int m0 = blockIdx.y * 128;
  const int wid = tid >> 6, lane = tid & 63;
  const int wr = (wid >> 1) * 64, wc = (wid & 1) * 64;
  const int r16 = lane & 15, quad = lane >> 4;
  const int ldsbase = (tid & ~63) * 8;   // wave-uniform ushort index

  // single staging pointer per matrix; slot i = +32*i*K (XOR term invariant)
  const int row0 = tid >> 3;
  const int cp0  = (tid & 7) ^ (row0 & 7);
  const unsigned short* pA0 = Ab + (size_t)(m0+row0)*K + cp0*8;
  const unsigned short* pB0 = BT + (size_t)(n0+row0)*K + cp0*8;
  const size_t slotStride = (size_t)32*K;

  // fragment LDS bases (ushort idx); mi adds 1024, ks=1 applies ^32
  const int swz = quad ^ (r16 & 7);
  const int abase = ((wr + r16)*8 + swz)*8;
  const int bbase = ((wc + r16)*8 + swz)*8;

  floatx4 acc[4][4];
  #pragma unroll
  for (int i=0;i<4;i++)
    #pragma unroll
    for (int j2=0;j2<4;j2++) acc[i][j2] = {0.f,0.f,0.f,0.f};

  for (int k0 = 0; k0 < K; k0 += 64) {
    #pragma unroll
    for (int i = 0; i < 4; ++i) async16(pA0 + i*slotStride, &As[ldsbase + i*2048]);
    #pragma unroll
    for (int i = 0; i < 4; ++i) async16(pB0 + i*slotStride, &Bs[ldsbase + i*2048]);
    __syncthreads();
    #pragma unroll
    for (int ks = 0; ks < 2; ++ks) {
      const int kx = ks*32;
      bhalf8 aF[4], bF[4];
      #pragma unroll
      for (int mi=0;mi<4;++mi) aF[mi] = *(const bhalf8*)&As[(abase + mi*1024) ^ kx];
      #pragma unroll
      for (int ni=0;ni<4;++ni) bF[ni] = *(const bhalf8*)&Bs[(bbase + ni*1024) ^ kx];
      #pragma unroll
      for (int mi=0;mi<4;++mi)
        #pragma unroll
        for (int ni=0;ni<4;++ni){
          if (EPI == 1 || EPI == 3)
            acc[mi][ni] = __builtin_amdgcn_mfma_f32_16x16x32_bf16(bF[ni], aF[mi], acc[mi][ni], 0, 0, 0);
          else
            acc[mi][ni] = __builtin_amdgcn_mfma_f32_16x16x32_bf16(aF[mi], bF[ni], acc[mi][ni], 0, 0, 0);
        }
    }
    __syncthreads();
    pA0 += 64; pB0 += 64;
  }

  if (EPI == 1 || EPI == 3) {
    // swapped layout: m = r16-based row, n = quad*4 + reg (4 consecutive n)
    #pragma unroll
    for (int mi=0;mi<4;++mi){
      const int m = m0 + wr + mi*16 + r16;
      #pragma unroll
      for (int ni=0;ni<4;++ni){
        const int n = n0 + wc + ni*16 + quad*4;
        float4 bv = *(const float4*)&bias[n];
        float v0 = acc[mi][ni][0] + bv.x;
        float v1 = acc[mi][ni][1] + bv.y;
        float v2 = acc[mi][ni][2] + bv.z;
        float v3 = acc[mi][ni][3] + bv.w;
        if (EPI == 1) {
          float4 st = make_float4(v0, v1, v2, v3);
          *(float4*)&Cf[(size_t)m*ldc + n] = st;
        } else {
          uint2 p;
          p.x = pack2(v0, v1);
          p.y = pack2(v2, v3);
          *(uint2*)&Cb[(size_t)m*ldc + n] = p;
        }
      }
    }
  } else {
    #pragma unroll
    for (int mi=0;mi<4;++mi)
      #pragma unroll
      for (int ni=0;ni<4;++ni)
        #pragma unroll
        for (int rr=0;rr<4;++rr){
          int m = m0 + wr + mi*16 + quad*4 + rr;
          int n = n0 + wc + ni*16 + r16;
          float val = acc[mi][ni][rr];
          if (EPI == 0) Cf[(size_t)m*ldc + n] = val;
          else Cb[(size_t)n*ldc + m] = f2bf(val);
        }
  }
}

// ---------------------------------------------------------------------------
// Fused prep: one launch for ALL elementwise prep.
//   [0,3072):        3x tiled transpose fp32[1024,1024] -> bf16 transposed
//   [3072,4096):     W_out fp32 -> bf16 copy
//   [4096,4160):     b_comb GEMV PARTIALS (64 blocks: 16 e-segs x 4 d-grps)
//   [4160,4168):     a_vec = exp(log_a); bcat = [b_ih | b_gate]
//   [4168,4168+32768): x fp32 -> bf16
// ---------------------------------------------------------------------------
__global__ __launch_bounds__(256) void prep_all(
    const float* __restrict__ W_ih, const float* __restrict__ W_gate,
    const float* __restrict__ W_proj, const float* __restrict__ W_out,
    const float* __restrict__ b_out,
    const float* __restrict__ log_a, const float* __restrict__ b_ih,
    const float* __restrict__ b_gate, const float* __restrict__ x,
    unsigned short* __restrict__ WcatT, unsigned short* __restrict__ WprojT,
    unsigned short* __restrict__ Woutb, unsigned short* __restrict__ xb,
    float* __restrict__ Pc, float* __restrict__ a_vec, float* __restrict__ bcat)
{
  __shared__ float tile[32][33];
  const int blk = blockIdx.x;
  const int tid = threadIdx.x;
  if (blk < 3072) {
    const int which = blk >> 10;
    const int t = blk & 1023;
    const float* src = (which == 0) ? W_ih : (which == 1) ? W_gate : W_proj;
    unsigned short* dst = (which == 0) ? WcatT : (which == 1) ? (WcatT + 1024*1024) : WprojT;
    const int c0 = (t & 31) * 32, r0 = (t >> 5) * 32;
    const int tx = tid & 31, ty = tid >> 5;       // 32 x 8
    #pragma unroll
    for (int i = 0; i < 32; i += 8)
      tile[ty+i][tx] = src[(size_t)(r0+ty+i)*1024 + c0+tx];
    __syncthreads();
    #pragma unroll
    for (int i = 0; i < 32; i += 8)
      dst[(size_t)(c0+ty+i)*1024 + r0+tx] = f2bf(tile[tx][ty+i]);
  } else if (blk < 4096) {
    int idx = ((blk - 3072)*256 + tid) * 4;
    float4 v = *(const float4*)(W_out + idx);
    uint2 p;
    p.x = pack2(v.x, v.y);
    p.y = pack2(v.z, v.w);
    *(uint2*)(Woutb + idx) = p;
  } else if (blk < 4160) {
    int blk2 = blk - 4096;
    int dgrp = blk2 >> 4, seg = blk2 & 15;
    int d = dgrp*256 + tid;
    int e0 = seg*64;
    float acc = 0.f;
    #pragma unroll 8
    for (int e = 0; e < 64; ++e)
      acc += b_out[e0+e] * W_proj[(size_t)(e0+e)*1024 + d];
    Pc[seg*1024 + d] = acc;
  } else if (blk < 4168) {
    int d = (blk - 4160)*256 + tid;  // 0..2047
    if (d < 1024) {
      a_vec[d] = __expf(log_a[d]);
      bcat[d] = b_ih[d];
    } else {
      bcat[d] = b_gate[d-1024];
    }
  } else {
    int idx = ((blk - 4168)*256 + tid) * 4;
    float4 v = *(const float4*)(x + idx);
    uint2 p;
    p.x = pack2(v.x, v.y);
    p.y = pack2(v.z, v.w);
    *(uint2*)(xb + idx) = p;
  }
}

// ---------------------------------------------------------------------------
// Chunked scan, CHUNK=16, NCHUNK=512. One WAVE owns all H=1024 channels
// (16 ch/lane) of one (b,chunk) unit.
// phase1 writes aggregates TRANSPOSED AsT/SsT[b][ch][c]; phase2 = one wave
// per (b,ch): 8 chunks/lane + 64-lane Hillis-Steele.
// R4: carry stored NON-transposed [b][c][ch] — phase2 scatter-writes
// (byte-enabled, no over-fetch), phase3 reads coalesced float4 (was a
// 4B/64B-line gather: 1024 lines/wave).
// ---------------------------------------------------------------------------
#define CHUNK 16
#define NCHUNK 512   // 8192 / CHUNK

__device__ __forceinline__ void ab_step(unsigned short iu, unsigned short gu,
                                        float a, float& al, float& be)
{
  float zi = bf2f(iu), zg = bf2f(gu);
  float g = 1.f / (1.f + __expf(-zg));
  al = (1.f - g) * a;
  be = g * zi;
}

__global__ __launch_bounds__(256, 4) void scan_phase1(const unsigned short* __restrict__ pre,
    const float* __restrict__ a_vec, float* __restrict__ AsT, float* __restrict__ SsT)
{
  __shared__ float sA[4][1024];
  __shared__ float sS[4][1024];
  int wid = threadIdx.x >> 6, lane = threadIdx.x & 63;
  int u = blockIdx.x*4 + wid;      // unit = b*NCHUNK + chunk, 2048 units
  int b = u >> 9, c = u & (NCHUNK-1);
  int ch0 = lane*16;
  float a[16], A[16], S[16];
  #pragma unroll
  for (int q=0;q<4;++q) *(float4*)&a[q*4] = *(const float4*)(a_vec + ch0 + q*4);
  #pragma unroll
  for (int j=0;j<16;++j){ A[j]=1.f; S[j]=0.f; }
  size_t base = ((size_t)(b*8192 + c*CHUNK))*2048 + ch0;
  for (int t=0;t<CHUNK;++t){
    ushortx8 i0 = *(const ushortx8*)(pre + base);
    ushortx8 i1 = *(const ushortx8*)(pre + base + 8);
    ushortx8 g0 = *(const ushortx8*)(pre + base + 1024);
    ushortx8 g1 = *(const ushortx8*)(pre + base + 1032);
    #pragma unroll
    for (int j=0;j<8;++j){
      float al, be;
      ab_step(i0[j], g0[j], a[j], al, be);
      A[j] *= al; S[j] = al*S[j] + be;
      ab_step(i1[j], g1[j], a[j+8], al, be);
      A[j+8] *= al; S[j+8] = al*S[j+8] + be;
    }
    base += 2048;
  }
  // LDS transpose: 4 units (consecutive c, same b) -> float4 over c
  #pragma unroll
  for (int j=0;j<16;++j){ sA[wid][ch0+j] = A[j]; sS[wid][ch0+j] = S[j]; }
  __syncthreads();
  const int bb = blockIdx.x >> 7;           // 128 blocks per batch
  const int c0 = (blockIdx.x*4) & (NCHUNK-1);
  const int t = threadIdx.x;
  #pragma unroll
  for (int q=0;q<4;++q){
    int ch = t + q*256;
    float4 va = make_float4(sA[0][ch], sA[1][ch], sA[2][ch], sA[3][ch]);
    float4 vs = make_float4(sS[0][ch], sS[1][ch], sS[2][ch], sS[3][ch]);
    size_t o = ((size_t)(bb*1024 + ch))*NCHUNK + c0;
    *(float4*)(AsT + o) = va;
    *(float4*)(SsT + o) = vs;
  }
}

// parallel inter-chunk scan: one wave per (b,ch) pair, 4096 pairs, 8 chunks/lane
// writes carry NON-transposed [b][c][ch] (scatter-writes, coalesced phase3 reads)
// block 0 additionally reduces b_comb = sum(Pc) + b_proj
__global__ __launch_bounds__(256) void scan_phase2(const float* __restrict__ AsT,
    const float* __restrict__ SsT, float* __restrict__ carry,
    const float* __restrict__ Pc, const float* __restrict__ b_proj,
    float* __restrict__ b_comb)
{
  int wid = threadIdx.x >> 6, lane = threadIdx.x & 63;
  int p = blockIdx.x*4 + wid;      // 0..4095 = b*1024 + ch
  size_t base = (size_t)p*NCHUNK + lane*8;
  float4 a0 = *(const float4*)(AsT + base);
  float4 a1 = *(const float4*)(AsT + base + 4);
  float4 s0 = *(const float4*)(SsT + base);
  float4 s1 = *(const float4*)(SsT + base + 4);
  // lane-internal aggregate over 8 chunks (ascending c)
  float A = a0.x, S = s0.x;
  A = a0.y*A; S = a0.y*S + s0.y;
  A = a0.z*A; S = a0.z*S + s0.z;
  A = a0.w*A; S = a0.w*S + s0.w;
  A = a1.x*A; S = a1.x*S + s1.x;
  A = a1.y*A; S = a1.y*S + s1.y;
  A = a1.z*A; S = a1.z*S + s1.z;
  A = a1.w*A; S = a1.w*S + s1.w;
  // inclusive Hillis-Steele over lanes
  float iA = A, iS = S;
  #pragma unroll
  for (int d = 1; d < 64; d <<= 1) {
    float pA = __shfl_up(iA, d);
    float pS = __shfl_up(iS, d);
    if (lane >= d) { iS = iA*pS + iS; iA = iA*pA; }
  }
  // exclusive base = inclusive of lane-1 (identity for lane 0); only S needed
  float bS = __shfl_up(iS, 1);
  if (lane == 0) bS = 0.f;
  const int b2 = p >> 10, ch = p & 1023;
  size_t o = ((size_t)b2*NCHUNK + lane*8)*1024 + ch;
  carry[o] = bS; bS = a0.x*bS + s0.x; o += 1024;
  carry[o] = bS; bS = a0.y*bS + s0.y; o += 1024;
  carry[o] = bS; bS = a0.z*bS + s0.z; o += 1024;
  carry[o] = bS; bS = a0.w*bS + s0.w; o += 1024;
  carry[o] = bS; bS = a1.x*bS + s1.x; o += 1024;
  carry[o] = bS; bS = a1.y*bS + s1.y; o += 1024;
  carry[o] = bS; bS = a1.z*bS + s1.z; o += 1024;
  carry[o] = bS;

  if (blockIdx.x == 0) {
    #pragma unroll
    for (int q = 0; q < 4; ++q) {
      int d = threadIdx.x + q*256;
      float acc = b_proj[d];
      #pragma unroll
      for (int s = 0; s < 16; ++s) acc += Pc[s*1024 + d];
      b_comb[d] = acc;
    }
  }
}

// phase3: recurrence + fused LayerNorm (wave-wide shfl_xor reduce) -> hn bf16
__global__ __launch_bounds__(256, 4) void scan_phase3(const unsigned short* __restrict__ pre,
    const float* __restrict__ a_vec, const float* __restrict__ carry,
    const float* __restrict__ ln_g, const float* __restrict__ ln_b,
    unsigned short* __restrict__ hn)
{
  int wid = threadIdx.x >> 6, lane = threadIdx.x & 63;
  int u = blockIdx.x*4 + wid;
  int b = u >> 9, c = u & (NCHUNK-1);
  int ch0 = lane*16;
  float a[16], h[16], g[16], lb[16];
  size_t co = ((size_t)b*NCHUNK + c)*1024 + ch0;
  #pragma unroll
  for (int q=0;q<4;++q){
    *(float4*)&a[q*4]  = *(const float4*)(a_vec + ch0 + q*4);
    *(float4*)&h[q*4]  = *(const float4*)(carry + co + q*4);
    *(float4*)&g[q*4]  = *(const float4*)(ln_g + ch0 + q*4);
    *(float4*)&lb[q*4] = *(const float4*)(ln_b + ch0 + q*4);
  }
  size_t base  = ((size_t)(b*8192 + c*CHUNK))*2048 + ch0;
  size_t hbase = ((size_t)(b*8192 + c*CHUNK))*1024 + ch0;
  for (int t=0;t<CHUNK;++t){
    ushortx8 i0 = *(const ushortx8*)(pre + base);
    ushortx8 i1 = *(const ushortx8*)(pre + base + 8);
    ushortx8 g0 = *(const ushortx8*)(pre + base + 1024);
    ushortx8 g1 = *(const ushortx8*)(pre + base + 1032);
    float s = 0.f, s2 = 0.f;
    #pragma unroll
    for (int j=0;j<8;++j){
      float al, be;
      ab_step(i0[j], g0[j], a[j], al, be);
      h[j] = al*h[j] + be;
      s += h[j]; s2 += h[j]*h[j];
      ab_step(i1[j], g1[j], a[j+8], al, be);
      h[j+8] = al*h[j+8] + be;
      s += h[j+8]; s2 += h[j+8]*h[j+8];
    }
    #pragma unroll
    for (int off = 32; off > 0; off >>= 1) {
      s  += __shfl_xor(s,  off);
      s2 += __shfl_xor(s2, off);
    }
    float mu = s * (1.f/1024.f);
    float var = s2 * (1.f/1024.f) - mu*mu;
    float rstd = rsqrtf(var + 1e-5f);
    uint4 o0, o1;
    float v0, v1;
    v0 = (h[0]-mu)*rstd*g[0]+lb[0];  v1 = (h[1]-mu)*rstd*g[1]+lb[1];  o0.x = pack2(v0,v1);
    v0 = (h[2]-mu)*rstd*g[2]+lb[2];  v1 = (h[3]-mu)*rstd*g[3]+lb[3];  o0.y = pack2(v0,v1);
    v0 = (h[4]-mu)*rstd*g[4]+lb[4];  v1 = (h[5]-mu)*rstd*g[5]+lb[5];  o0.z = pack2(v0,v1);
    v0 = (h[6]-mu)*rstd*g[6]+lb[6];  v1 = (h[7]-mu)*rstd*g[7]+lb[7];  o0.w = pack2(v0,v1);
    v0 = (h[8]-mu)*rstd*g[8]+lb[8];  v1 = (h[9]-mu)*rstd*g[9]+lb[9];  o1.x = pack2(v0,v1);
    v0 = (h[10]-mu)*rstd*g[10]+lb[10]; v1 = (h[11]-mu)*rstd*g[11]+lb[11]; o1.y = pack2(v0,v1);
    v0 = (h[12]-mu)*rstd*g[12]+lb[12]; v1 = (h[13]-mu)*rstd*g[13]+lb[13]; o1.z = pack2(v0,v1);
    v0 = (h[14]-mu)*rstd*g[14]+lb[14]; v1 = (h[15]-mu)*rstd*g[15]+lb[15]; o1.w = pack2(v0,v1);
    *(uint4*)(hn + hbase)     = o0;
    *(uint4*)(hn + hbase + 8) = o1;
    base += 2048; hbase += 1024;
  }
}

extern "C" void kernel_launch(void* const* d_in, const int* in_sizes, int n_in,
                              void* d_out, int out_size, void* d_ws, size_t ws_size,
                              hipStream_t stream)
{
  const float* x      = (const float*)d_in[0];
  const float* W_ih   = (const float*)d_in[1];
  const float* b_ih   = (const float*)d_in[2];
  const float* W_gate = (const float*)d_in[3];
  const float* b_gate = (const float*)d_in[4];
  const float* log_a  = (const float*)d_in[5];
  const float* ln_g   = (const float*)d_in[6];
  const float* ln_b   = (const float*)d_in[7];
  const float* W_out  = (const float*)d_in[8];
  const float* b_out  = (const float*)d_in[9];
  const float* W_proj = (const float*)d_in[10];
  const float* b_proj = (const float*)d_in[11];
  float* out = (float*)d_out;

  char* ws = (char*)d_ws;
  size_t off = 0;
  auto alloc = [&](size_t bytes)->char* {
    char* p = ws + off; off += (bytes + 255) & ~(size_t)255; return p;
  };
  unsigned short* pre   = (unsigned short*)alloc((size_t)32768*2048*2); // 128 MB bf16
  unsigned short* hn    = (unsigned short*)alloc((size_t)32768*1024*2); // 64 MB (aliased w/ xb)
  unsigned short* xb    = hn;   // x bf16; dead before hn is written
  unsigned short* WcatT = (unsigned short*)alloc((size_t)2048*1024*2);
  unsigned short* WprojT= (unsigned short*)alloc((size_t)1024*1024*2);
  unsigned short* Woutb = (unsigned short*)alloc((size_t)1024*1024*2);
  unsigned short* WcombT= (unsigned short*)alloc((size_t)1024*1024*2);
  float* AsT            = (float*)alloc((size_t)4*1024*NCHUNK*4);  // 8 MB [b][ch][c]
  float* SsT            = (float*)alloc((size_t)4*1024*NCHUNK*4);
  float* carry          = (float*)alloc((size_t)4*NCHUNK*1024*4);  // 8 MB [b][c][ch]
  float* Pc             = (float*)alloc((size_t)16*1024*4);        // b_comb partials
  float* b_comb         = (float*)alloc(1024*4);
  float* a_vec          = (float*)alloc(1024*4);
  float* bcat           = (float*)alloc(2048*4);

  // fused prep: transposes + W_out cvt + b_comb partials + small vecs + x cvt
  prep_all<<<4168 + 32768, 256, 0, stream>>>(W_ih, W_gate, W_proj, W_out, b_out,
                                             log_a, b_ih, b_gate, x,
                                             WcatT, WprojT, Woutb, xb,
                                             Pc, a_vec, bcat);
  // WcombT = (W_out @ W_proj)^T
  gemm_k<2><<<dim3(8,8), 256, 0, stream>>>(Woutb, WprojT, nullptr, nullptr, WcombT, 1024, 1024);
  // pre[M,2048] = bf16(x @ [W_ih|W_gate] + bcat)
  gemm_k<3><<<dim3(16,256), 256, 0, stream>>>(xb, WcatT, bcat, nullptr, pre, 1024, 2048);
  // chunked scan (chunk=16) + fused LN, parallel inter-chunk scan
  scan_phase1<<<512, 256, 0, stream>>>(pre, a_vec, AsT, SsT);
  scan_phase2<<<1024, 256, 0, stream>>>(AsT, SsT, carry, Pc, b_proj, b_comb);
  scan_phase3<<<512, 256, 0, stream>>>(pre, a_vec, carry, ln_g, ln_b, hn);
  // out = hn @ Wcomb + b_comb
  gemm_k<1><<<dim3(8,256), 256, 0, stream>>>(hn, WcombT, b_comb, out, nullptr, 1024, 1024);
}

// Round 5
// 615.742 us; speedup vs baseline: 1.0675x; 1.0675x over previous
//
#include <hip/hip_runtime.h>

typedef short bhalf8 __attribute__((ext_vector_type(8)));
typedef float floatx4 __attribute__((ext_vector_type(4)));
typedef unsigned short ushortx8 __attribute__((ext_vector_type(8)));

__device__ __forceinline__ unsigned short f2bf(float f){
  union { float f; unsigned int u; } v; v.f = f;
  unsigned int u = v.u;
  u += 0x7fffu + ((u >> 16) & 1u);
  return (unsigned short)(u >> 16);
}
__device__ __forceinline__ float bf2f(unsigned short u){
  union { unsigned int u; float f; } v; v.u = ((unsigned)u) << 16; return v.f;
}
__device__ __forceinline__ unsigned pack2(float a, float b){
  return (unsigned)f2bf(a) | ((unsigned)f2bf(b) << 16);
}

__device__ __forceinline__ void async16(const unsigned short* g, unsigned short* l){
  __builtin_amdgcn_global_load_lds(
      (const __attribute__((address_space(1))) void*)g,
      (__attribute__((address_space(3))) void*)l,
      16, 0, 0);
}

// ---------------------------------------------------------------------------
// MFMA GEMM — EXACT R3 version (188 us, VGPR 88, MfmaUtil 32%).
// R4's operand-swap + "register diet" REVERTED (208 us, MfmaUtil 28.5%:
// main-loop scheduling regressed; per-access XOR addr math + rematerialized
// 64-bit staging addresses beat the cheap persistent-pointer increments).
// Tile 128x128, BK=64 (32 KB LDS), 4 waves 2x2, 4x4 mfma_f32_16x16x32_bf16.
// Staging: global_load_lds w=16, XOR swizzle slot=(row*8 + (c ^ (row&7))).
// EPI 0: fp32 C;  1: fp32 C+bias;  2: bf16 transposed;  3: bf16 C+bias
// ---------------------------------------------------------------------------
template<int EPI>
__global__ __launch_bounds__(256) void gemm_k(
    const unsigned short* __restrict__ Ab, const unsigned short* __restrict__ BT,
    const float* __restrict__ bias, float* __restrict__ Cf,
    unsigned short* __restrict__ Cb, int K, int ldc)
{
  __shared__ __align__(16) unsigned short As[128*64];
  __shared__ __align__(16) unsigned short Bs[128*64];
  const int tid = threadIdx.x;
  const int n0 = blockIdx.x * 128;
  const int m0 = blockIdx.y * 128;
  const int wid = tid >> 6, lane = tid & 63;
  const int wr = (wid >> 1) * 64, wc = (wid & 1) * 64;
  const int r16 = lane & 15, quad = lane >> 4;
  const int ldsbase = (tid & ~63) * 8;   // wave-uniform ushort index

  const unsigned short* pA[4];
  const unsigned short* pB[4];
  #pragma unroll
  for (int i = 0; i < 4; ++i) {
    int p = tid + i*256;
    int row = p >> 3;
    int cp = (p & 7) ^ (row & 7);
    pA[i] = Ab + (size_t)(m0+row)*K + cp*8;
    pB[i] = BT + (size_t)(n0+row)*K + cp*8;
  }
  int aoff[2][4], boff[2][4];
  #pragma unroll
  for (int ks = 0; ks < 2; ++ks){
    #pragma unroll
    for (int mi = 0; mi < 4; ++mi){
      int row = wr + mi*16 + r16;
      aoff[ks][mi] = (row*8 + ((ks*4+quad) ^ (row&7))) * 8;
    }
    #pragma unroll
    for (int ni = 0; ni < 4; ++ni){
      int row = wc + ni*16 + r16;
      boff[ks][ni] = (row*8 + ((ks*4+quad) ^ (row&7))) * 8;
    }
  }

  floatx4 acc[4][4];
  #pragma unroll
  for (int i=0;i<4;i++)
    #pragma unroll
    for (int j2=0;j2<4;j2++) acc[i][j2] = {0.f,0.f,0.f,0.f};

  for (int k0 = 0; k0 < K; k0 += 64) {
    #pragma unroll
    for (int i = 0; i < 4; ++i) async16(pA[i], &As[ldsbase + i*2048]);
    #pragma unroll
    for (int i = 0; i < 4; ++i) async16(pB[i], &Bs[ldsbase + i*2048]);
    __syncthreads();
    #pragma unroll
    for (int ks = 0; ks < 2; ++ks) {
      bhalf8 aF[4], bF[4];
      #pragma unroll
      for (int mi=0;mi<4;++mi) aF[mi] = *(const bhalf8*)&As[aoff[ks][mi]];
      #pragma unroll
      for (int ni=0;ni<4;++ni) bF[ni] = *(const bhalf8*)&Bs[boff[ks][ni]];
      #pragma unroll
      for (int mi=0;mi<4;++mi)
        #pragma unroll
        for (int ni=0;ni<4;++ni)
          acc[mi][ni] = __builtin_amdgcn_mfma_f32_16x16x32_bf16(aF[mi], bF[ni], acc[mi][ni], 0, 0, 0);
    }
    __syncthreads();
    #pragma unroll
    for (int i = 0; i < 4; ++i) { pA[i] += 64; pB[i] += 64; }
  }

  #pragma unroll
  for (int mi=0;mi<4;++mi)
    #pragma unroll
    for (int ni=0;ni<4;++ni)
      #pragma unroll
      for (int rr=0;rr<4;++rr){
        int m = m0 + wr + mi*16 + quad*4 + rr;
        int n = n0 + wc + ni*16 + r16;
        float val = acc[mi][ni][rr];
        if (EPI == 0) Cf[(size_t)m*ldc + n] = val;
        else if (EPI == 1) Cf[(size_t)m*ldc + n] = val + bias[n];
        else if (EPI == 3) Cb[(size_t)m*ldc + n] = f2bf(val + bias[n]);
        else Cb[(size_t)n*ldc + m] = f2bf(val);
      }
}

// ---------------------------------------------------------------------------
// Fused prep: one launch for ALL elementwise prep.
//   [0,3072):        3x tiled transpose fp32[1024,1024] -> bf16 transposed
//   [3072,4096):     W_out fp32 -> bf16 copy
//   [4096,4160):     b_comb GEMV PARTIALS (64 blocks: 16 e-segs x 4 d-grps)
//   [4160,4168):     a_vec = exp(log_a); bcat = [b_ih | b_gate]
//   [4168,4168+32768): x fp32 -> bf16
// ---------------------------------------------------------------------------
__global__ __launch_bounds__(256) void prep_all(
    const float* __restrict__ W_ih, const float* __restrict__ W_gate,
    const float* __restrict__ W_proj, const float* __restrict__ W_out,
    const float* __restrict__ b_out,
    const float* __restrict__ log_a, const float* __restrict__ b_ih,
    const float* __restrict__ b_gate, const float* __restrict__ x,
    unsigned short* __restrict__ WcatT, unsigned short* __restrict__ WprojT,
    unsigned short* __restrict__ Woutb, unsigned short* __restrict__ xb,
    float* __restrict__ Pc, float* __restrict__ a_vec, float* __restrict__ bcat)
{
  __shared__ float tile[32][33];
  const int blk = blockIdx.x;
  const int tid = threadIdx.x;
  if (blk < 3072) {
    const int which = blk >> 10;
    const int t = blk & 1023;
    const float* src = (which == 0) ? W_ih : (which == 1) ? W_gate : W_proj;
    unsigned short* dst = (which == 0) ? WcatT : (which == 1) ? (WcatT + 1024*1024) : WprojT;
    const int c0 = (t & 31) * 32, r0 = (t >> 5) * 32;
    const int tx = tid & 31, ty = tid >> 5;       // 32 x 8
    #pragma unroll
    for (int i = 0; i < 32; i += 8)
      tile[ty+i][tx] = src[(size_t)(r0+ty+i)*1024 + c0+tx];
    __syncthreads();
    #pragma unroll
    for (int i = 0; i < 32; i += 8)
      dst[(size_t)(c0+ty+i)*1024 + r0+tx] = f2bf(tile[tx][ty+i]);
  } else if (blk < 4096) {
    int idx = ((blk - 3072)*256 + tid) * 4;
    float4 v = *(const float4*)(W_out + idx);
    uint2 p;
    p.x = pack2(v.x, v.y);
    p.y = pack2(v.z, v.w);
    *(uint2*)(Woutb + idx) = p;
  } else if (blk < 4160) {
    int blk2 = blk - 4096;
    int dgrp = blk2 >> 4, seg = blk2 & 15;
    int d = dgrp*256 + tid;
    int e0 = seg*64;
    float acc = 0.f;
    #pragma unroll 8
    for (int e = 0; e < 64; ++e)
      acc += b_out[e0+e] * W_proj[(size_t)(e0+e)*1024 + d];
    Pc[seg*1024 + d] = acc;
  } else if (blk < 4168) {
    int d = (blk - 4160)*256 + tid;  // 0..2047
    if (d < 1024) {
      a_vec[d] = __expf(log_a[d]);
      bcat[d] = b_ih[d];
    } else {
      bcat[d] = b_gate[d-1024];
    }
  } else {
    int idx = ((blk - 4168)*256 + tid) * 4;
    float4 v = *(const float4*)(x + idx);
    uint2 p;
    p.x = pack2(v.x, v.y);
    p.y = pack2(v.z, v.w);
    *(uint2*)(xb + idx) = p;
  }
}

// ---------------------------------------------------------------------------
// Chunked scan, CHUNK=16, NCHUNK=512. One WAVE owns all H=1024 channels
// (16 ch/lane) of one (b,chunk) unit.
// R5: ab_step sigmoid via __builtin_amdgcn_rcpf — without fast-math,
// `1.f/(1.f+e)` compiled to the ~12-instr precise-divide sequence
// (v_div_scale/fmas/fixup) x16ch x2 phases x8192 t = the scan phases'
// VALU bottleneck. rsqrtf -> __builtin_amdgcn_rsqf likewise (LN).
// carry stored NON-transposed [b][c][ch] (R4 win kept): phase2
// scatter-writes, phase3 reads coalesced float4.
// ---------------------------------------------------------------------------
#define CHUNK 16
#define NCHUNK 512   // 8192 / CHUNK

__device__ __forceinline__ void ab_step(unsigned short iu, unsigned short gu,
                                        float a, float& al, float& be)
{
  float zi = bf2f(iu), zg = bf2f(gu);
  float g = __builtin_amdgcn_rcpf(1.f + __expf(-zg));   // v_rcp_f32, ~1ulp
  al = (1.f - g) * a;
  be = g * zi;
}

__global__ __launch_bounds__(256, 4) void scan_phase1(const unsigned short* __restrict__ pre,
    const float* __restrict__ a_vec, float* __restrict__ AsT, float* __restrict__ SsT)
{
  __shared__ float sA[4][1024];
  __shared__ float sS[4][1024];
  int wid = threadIdx.x >> 6, lane = threadIdx.x & 63;
  int u = blockIdx.x*4 + wid;      // unit = b*NCHUNK + chunk, 2048 units
  int b = u >> 9, c = u & (NCHUNK-1);
  int ch0 = lane*16;
  float a[16], A[16], S[16];
  #pragma unroll
  for (int q=0;q<4;++q) *(float4*)&a[q*4] = *(const float4*)(a_vec + ch0 + q*4);
  #pragma unroll
  for (int j=0;j<16;++j){ A[j]=1.f; S[j]=0.f; }
  size_t base = ((size_t)(b*8192 + c*CHUNK))*2048 + ch0;
  for (int t=0;t<CHUNK;++t){
    ushortx8 i0 = *(const ushortx8*)(pre + base);
    ushortx8 i1 = *(const ushortx8*)(pre + base + 8);
    ushortx8 g0 = *(const ushortx8*)(pre + base + 1024);
    ushortx8 g1 = *(const ushortx8*)(pre + base + 1032);
    #pragma unroll
    for (int j=0;j<8;++j){
      float al, be;
      ab_step(i0[j], g0[j], a[j], al, be);
      A[j] *= al; S[j] = al*S[j] + be;
      ab_step(i1[j], g1[j], a[j+8], al, be);
      A[j+8] *= al; S[j+8] = al*S[j+8] + be;
    }
    base += 2048;
  }
  // LDS transpose: 4 units (consecutive c, same b) -> float4 over c
  #pragma unroll
  for (int j=0;j<16;++j){ sA[wid][ch0+j] = A[j]; sS[wid][ch0+j] = S[j]; }
  __syncthreads();
  const int bb = blockIdx.x >> 7;           // 128 blocks per batch
  const int c0 = (blockIdx.x*4) & (NCHUNK-1);
  const int t = threadIdx.x;
  #pragma unroll
  for (int q=0;q<4;++q){
    int ch = t + q*256;
    float4 va = make_float4(sA[0][ch], sA[1][ch], sA[2][ch], sA[3][ch]);
    float4 vs = make_float4(sS[0][ch], sS[1][ch], sS[2][ch], sS[3][ch]);
    size_t o = ((size_t)(bb*1024 + ch))*NCHUNK + c0;
    *(float4*)(AsT + o) = va;
    *(float4*)(SsT + o) = vs;
  }
}

// parallel inter-chunk scan: one wave per (b,ch) pair, 4096 pairs, 8 chunks/lane
// writes carry NON-transposed [b][c][ch]; block 0 reduces b_comb
__global__ __launch_bounds__(256) void scan_phase2(const float* __restrict__ AsT,
    const float* __restrict__ SsT, float* __restrict__ carry,
    const float* __restrict__ Pc, const float* __restrict__ b_proj,
    float* __restrict__ b_comb)
{
  int wid = threadIdx.x >> 6, lane = threadIdx.x & 63;
  int p = blockIdx.x*4 + wid;      // 0..4095 = b*1024 + ch
  size_t base = (size_t)p*NCHUNK + lane*8;
  float4 a0 = *(const float4*)(AsT + base);
  float4 a1 = *(const float4*)(AsT + base + 4);
  float4 s0 = *(const float4*)(SsT + base);
  float4 s1 = *(const float4*)(SsT + base + 4);
  // lane-internal aggregate over 8 chunks (ascending c)
  float A = a0.x, S = s0.x;
  A = a0.y*A; S = a0.y*S + s0.y;
  A = a0.z*A; S = a0.z*S + s0.z;
  A = a0.w*A; S = a0.w*S + s0.w;
  A = a1.x*A; S = a1.x*S + s1.x;
  A = a1.y*A; S = a1.y*S + s1.y;
  A = a1.z*A; S = a1.z*S + s1.z;
  A = a1.w*A; S = a1.w*S + s1.w;
  // inclusive Hillis-Steele over lanes
  float iA = A, iS = S;
  #pragma unroll
  for (int d = 1; d < 64; d <<= 1) {
    float pA = __shfl_up(iA, d);
    float pS = __shfl_up(iS, d);
    if (lane >= d) { iS = iA*pS + iS; iA = iA*pA; }
  }
  // exclusive base = inclusive of lane-1 (identity for lane 0); only S needed
  float bS = __shfl_up(iS, 1);
  if (lane == 0) bS = 0.f;
  const int b2 = p >> 10, ch = p & 1023;
  size_t o = ((size_t)b2*NCHUNK + lane*8)*1024 + ch;
  carry[o] = bS; bS = a0.x*bS + s0.x; o += 1024;
  carry[o] = bS; bS = a0.y*bS + s0.y; o += 1024;
  carry[o] = bS; bS = a0.z*bS + s0.z; o += 1024;
  carry[o] = bS; bS = a0.w*bS + s0.w; o += 1024;
  carry[o] = bS; bS = a1.x*bS + s1.x; o += 1024;
  carry[o] = bS; bS = a1.y*bS + s1.y; o += 1024;
  carry[o] = bS; bS = a1.z*bS + s1.z; o += 1024;
  carry[o] = bS;

  if (blockIdx.x == 0) {
    #pragma unroll
    for (int q = 0; q < 4; ++q) {
      int d = threadIdx.x + q*256;
      float acc = b_proj[d];
      #pragma unroll
      for (int s = 0; s < 16; ++s) acc += Pc[s*1024 + d];
      b_comb[d] = acc;
    }
  }
}

// phase3: recurrence + fused LayerNorm (wave-wide shfl_xor reduce) -> hn bf16
__global__ __launch_bounds__(256, 4) void scan_phase3(const unsigned short* __restrict__ pre,
    const float* __restrict__ a_vec, const float* __restrict__ carry,
    const float* __restrict__ ln_g, const float* __restrict__ ln_b,
    unsigned short* __restrict__ hn)
{
  int wid = threadIdx.x >> 6, lane = threadIdx.x & 63;
  int u = blockIdx.x*4 + wid;
  int b = u >> 9, c = u & (NCHUNK-1);
  int ch0 = lane*16;
  float a[16], h[16], g[16], lb[16];
  size_t co = ((size_t)b*NCHUNK + c)*1024 + ch0;
  #pragma unroll
  for (int q=0;q<4;++q){
    *(float4*)&a[q*4]  = *(const float4*)(a_vec + ch0 + q*4);
    *(float4*)&h[q*4]  = *(const float4*)(carry + co + q*4);
    *(float4*)&g[q*4]  = *(const float4*)(ln_g + ch0 + q*4);
    *(float4*)&lb[q*4] = *(const float4*)(ln_b + ch0 + q*4);
  }
  size_t base  = ((size_t)(b*8192 + c*CHUNK))*2048 + ch0;
  size_t hbase = ((size_t)(b*8192 + c*CHUNK))*1024 + ch0;
  for (int t=0;t<CHUNK;++t){
    ushortx8 i0 = *(const ushortx8*)(pre + base);
    ushortx8 i1 = *(const ushortx8*)(pre + base + 8);
    ushortx8 g0 = *(const ushortx8*)(pre + base + 1024);
    ushortx8 g1 = *(const ushortx8*)(pre + base + 1032);
    float s = 0.f, s2 = 0.f;
    #pragma unroll
    for (int j=0;j<8;++j){
      float al, be;
      ab_step(i0[j], g0[j], a[j], al, be);
      h[j] = al*h[j] + be;
      s += h[j]; s2 += h[j]*h[j];
      ab_step(i1[j], g1[j], a[j+8], al, be);
      h[j+8] = al*h[j+8] + be;
      s += h[j+8]; s2 += h[j+8]*h[j+8];
    }
    #pragma unroll
    for (int off = 32; off > 0; off >>= 1) {
      s  += __shfl_xor(s,  off);
      s2 += __shfl_xor(s2, off);
    }
    float mu = s * (1.f/1024.f);
    float var = s2 * (1.f/1024.f) - mu*mu;
    float rstd = __builtin_amdgcn_rsqf(var + 1e-5f);   // v_rsq_f32
    uint4 o0, o1;
    float v0, v1;
    v0 = (h[0]-mu)*rstd*g[0]+lb[0];  v1 = (h[1]-mu)*rstd*g[1]+lb[1];  o0.x = pack2(v0,v1);
    v0 = (h[2]-mu)*rstd*g[2]+lb[2];  v1 = (h[3]-mu)*rstd*g[3]+lb[3];  o0.y = pack2(v0,v1);
    v0 = (h[4]-mu)*rstd*g[4]+lb[4];  v1 = (h[5]-mu)*rstd*g[5]+lb[5];  o0.z = pack2(v0,v1);
    v0 = (h[6]-mu)*rstd*g[6]+lb[6];  v1 = (h[7]-mu)*rstd*g[7]+lb[7];  o0.w = pack2(v0,v1);
    v0 = (h[8]-mu)*rstd*g[8]+lb[8];  v1 = (h[9]-mu)*rstd*g[9]+lb[9];  o1.x = pack2(v0,v1);
    v0 = (h[10]-mu)*rstd*g[10]+lb[10]; v1 = (h[11]-mu)*rstd*g[11]+lb[11]; o1.y = pack2(v0,v1);
    v0 = (h[12]-mu)*rstd*g[12]+lb[12]; v1 = (h[13]-mu)*rstd*g[13]+lb[13]; o1.z = pack2(v0,v1);
    v0 = (h[14]-mu)*rstd*g[14]+lb[14]; v1 = (h[15]-mu)*rstd*g[15]+lb[15]; o1.w = pack2(v0,v1);
    *(uint4*)(hn + hbase)     = o0;
    *(uint4*)(hn + hbase + 8) = o1;
    base += 2048; hbase += 1024;
  }
}

extern "C" void kernel_launch(void* const* d_in, const int* in_sizes, int n_in,
                              void* d_out, int out_size, void* d_ws, size_t ws_size,
                              hipStream_t stream)
{
  const float* x      = (const float*)d_in[0];
  const float* W_ih   = (const float*)d_in[1];
  const float* b_ih   = (const float*)d_in[2];
  const float* W_gate = (const float*)d_in[3];
  const float* b_gate = (const float*)d_in[4];
  const float* log_a  = (const float*)d_in[5];
  const float* ln_g   = (const float*)d_in[6];
  const float* ln_b   = (const float*)d_in[7];
  const float* W_out  = (const float*)d_in[8];
  const float* b_out  = (const float*)d_in[9];
  const float* W_proj = (const float*)d_in[10];
  const float* b_proj = (const float*)d_in[11];
  float* out = (float*)d_out;

  char* ws = (char*)d_ws;
  size_t off = 0;
  auto alloc = [&](size_t bytes)->char* {
    char* p = ws + off; off += (bytes + 255) & ~(size_t)255; return p;
  };
  unsigned short* pre   = (unsigned short*)alloc((size_t)32768*2048*2); // 128 MB bf16
  unsigned short* hn    = (unsigned short*)alloc((size_t)32768*1024*2); // 64 MB (aliased w/ xb)
  unsigned short* xb    = hn;   // x bf16; dead before hn is written
  unsigned short* WcatT = (unsigned short*)alloc((size_t)2048*1024*2);
  unsigned short* WprojT= (unsigned short*)alloc((size_t)1024*1024*2);
  unsigned short* Woutb = (unsigned short*)alloc((size_t)1024*1024*2);
  unsigned short* WcombT= (unsigned short*)alloc((size_t)1024*1024*2);
  float* AsT            = (float*)alloc((size_t)4*1024*NCHUNK*4);  // 8 MB [b][ch][c]
  float* SsT            = (float*)alloc((size_t)4*1024*NCHUNK*4);
  float* carry          = (float*)alloc((size_t)4*NCHUNK*1024*4);  // 8 MB [b][c][ch]
  float* Pc             = (float*)alloc((size_t)16*1024*4);        // b_comb partials
  float* b_comb         = (float*)alloc(1024*4);
  float* a_vec          = (float*)alloc(1024*4);
  float* bcat           = (float*)alloc(2048*4);

  // fused prep: transposes + W_out cvt + b_comb partials + small vecs + x cvt
  prep_all<<<4168 + 32768, 256, 0, stream>>>(W_ih, W_gate, W_proj, W_out, b_out,
                                             log_a, b_ih, b_gate, x,
                                             WcatT, WprojT, Woutb, xb,
                                             Pc, a_vec, bcat);
  // WcombT = (W_out @ W_proj)^T
  gemm_k<2><<<dim3(8,8), 256, 0, stream>>>(Woutb, WprojT, nullptr, nullptr, WcombT, 1024, 1024);
  // pre[M,2048] = bf16(x @ [W_ih|W_gate] + bcat)
  gemm_k<3><<<dim3(16,256), 256, 0, stream>>>(xb, WcatT, bcat, nullptr, pre, 1024, 2048);
  // chunked scan (chunk=16) + fused LN, parallel inter-chunk scan
  scan_phase1<<<512, 256, 0, stream>>>(pre, a_vec, AsT, SsT);
  scan_phase2<<<1024, 256, 0, stream>>>(AsT, SsT, carry, Pc, b_proj, b_comb);
  scan_phase3<<<512, 256, 0, stream>>>(pre, a_vec, carry, ln_g, ln_b, hn);
  // out = hn @ Wcomb + b_comb
  gemm_k<1><<<dim3(8,256), 256, 0, stream>>>(hn, WcombT, b_comb, out, nullptr, 1024, 1024);
}